// Round 1
// baseline (1472.641 us; speedup 1.0000x reference)
//
#include <hip/hip_runtime.h>
#include <math.h>

// Problem constants
static constexpr int Bn = 2048;   // batch
static constexpr int Nn = 256;    // memory locations
static constexpr int Mn = 128;    // memory width
static constexpr int Un = 512;    // units

// Workspace layout (float offsets)
static constexpr size_t OFF_H0C   = 0;                                  // 512
static constexpr size_t OFF_Z0C   = 512;                                // 2048
static constexpr size_t OFF_Z1C   = 2560;                               // 2048
static constexpr size_t OFF_MNORM = 4608;                               // 256
static constexpr size_t OFF_APREV = 4864;                               // 4*256
static constexpr size_t OFF_BRW   = 5888;                               // 1048
static constexpr size_t OFF_KNORM = 6936;                               // 8192
static constexpr size_t OFF_XH    = 16384;                              // B*1024 (later reused as kbuf)
static constexpr size_t OFF_ZBUF  = OFF_XH + (size_t)Bn * 1024;         // B*2048 (later reused as Kmat)
static constexpr size_t OFF_HR    = OFF_ZBUF + (size_t)Bn * 2048;       // B*768
static constexpr size_t OFF_HEADS = OFF_HR + (size_t)Bn * 768;          // B*1048
static constexpr size_t OFF_WRW   = OFF_HEADS + (size_t)Bn * 1048;      // 512*1048
static constexpr size_t OFF_M0T   = OFF_WRW + (size_t)512 * 1048;       // 128*256
static constexpr size_t OFF_AT    = OFF_M0T + 32768;                    // 4*B*256
static constexpr size_t OFF_ERA   = OFF_AT + (size_t)4 * Bn * 256;      // B*2*128
static constexpr size_t OFF_ADD   = OFF_ERA + (size_t)Bn * 2 * 128;     // B*2*128

#define DEV __device__ __forceinline__

DEV float sigf(float x) { return 1.0f / (1.0f + expf(-x)); }
DEV float softplusf(float x) { return x > 20.0f ? x : log1pf(expf(x)); }

DEV float blk_reduce_max(float v, float* red) {
    int tid = threadIdx.x;
    red[tid] = v; __syncthreads();
    for (int s = (int)blockDim.x >> 1; s > 0; s >>= 1) {
        if (tid < s) red[tid] = fmaxf(red[tid], red[tid + s]);
        __syncthreads();
    }
    float r = red[0]; __syncthreads();
    return r;
}
DEV float blk_reduce_sum(float v, float* red) {
    int tid = threadIdx.x;
    red[tid] = v; __syncthreads();
    for (int s = (int)blockDim.x >> 1; s > 0; s >>= 1) {
        if (tid < s) red[tid] += red[tid + s];
        __syncthreads();
    }
    float r = red[0]; __syncthreads();
    return r;
}

// ---------------------------------------------------------------------------
// Generic f32 GEMM: C[m,n] = sum_k A[m,k]*W[k,n] (+ bias[n]) (+ clip)
// Block tile 128x128, 256 threads, thread tile 8x8, BK=16.
// ---------------------------------------------------------------------------
__global__ __launch_bounds__(256) void gemm_f32(
    const float* __restrict__ A, int lda,
    const float* __restrict__ W, int ldw,
    const float* __restrict__ bias,
    float* __restrict__ C, int ldc,
    int Mr, int Nr, int Kr, int epi)
{
    __shared__ float As[16][132];   // [k][m], padded stride 132 (16B aligned, conflict-free)
    __shared__ float Ws[16][128];   // [k][n]
    const int tid = threadIdx.x;
    const int tx = tid & 15, ty = tid >> 4;
    const int row0 = blockIdx.x * 128;
    const int col0 = blockIdx.y * 128;
    const int tm0 = ty * 8, tn0 = tx * 8;
    float acc[8][8];
    #pragma unroll
    for (int i = 0; i < 8; ++i)
        #pragma unroll
        for (int j = 0; j < 8; ++j) acc[i][j] = 0.f;

    for (int k0 = 0; k0 < Kr; k0 += 16) {
        // A tile: 128 rows x 16 k, 8 elems/thread (k fastest -> coalesced rows)
        #pragma unroll
        for (int i = tid; i < 128 * 16; i += 256) {
            int m = i >> 4, k = i & 15;
            int gm = row0 + m, gk = k0 + k;
            float v = 0.f;
            if (gm < Mr && gk < Kr) v = A[(size_t)gm * lda + gk];
            As[k][m] = v;
        }
        // W tile: 16 k x 128 n (n fastest -> coalesced)
        #pragma unroll
        for (int i = tid; i < 16 * 128; i += 256) {
            int k = i >> 7, n = i & 127;
            int gk = k0 + k, gn = col0 + n;
            float v = 0.f;
            if (gk < Kr && gn < Nr) v = W[(size_t)gk * ldw + gn];
            Ws[k][n] = v;
        }
        __syncthreads();
        #pragma unroll
        for (int k = 0; k < 16; ++k) {
            float a[8], b[8];
            #pragma unroll
            for (int i = 0; i < 8; ++i) a[i] = As[k][tm0 + i];
            #pragma unroll
            for (int j = 0; j < 8; ++j) b[j] = Ws[k][tn0 + j];
            #pragma unroll
            for (int i = 0; i < 8; ++i)
                #pragma unroll
                for (int j = 0; j < 8; ++j)
                    acc[i][j] = fmaf(a[i], b[j], acc[i][j]);
        }
        __syncthreads();
    }
    #pragma unroll
    for (int i = 0; i < 8; ++i) {
        int gm = row0 + tm0 + i;
        if (gm >= Mr) continue;
        #pragma unroll
        for (int j = 0; j < 8; ++j) {
            int gn = col0 + tn0 + j;
            if (gn >= Nr) continue;
            float v = acc[i][j];
            if (bias) v += bias[gn];
            if (epi == 1) v = fminf(fmaxf(v, -20.f), 20.f);
            C[(size_t)gm * ldc + gn] = v;
        }
    }
}

// ---------------------------------------------------------------------------
// Batch-invariant constants: r0cat=tanh(R0), h0 = r0cat@W_prep+b_prep,
// a_prev[i] = softmax(A0[i]), m_norm[n] = ||m0[n]||
// ---------------------------------------------------------------------------
__global__ __launch_bounds__(256) void k_const_a(
    const float* __restrict__ R0, const float* __restrict__ W_prep,
    const float* __restrict__ b_prep, const float* __restrict__ A0,
    const float* __restrict__ m0, float* __restrict__ ws)
{
    __shared__ float r0s[256];
    __shared__ float red[256];
    const int tid = threadIdx.x;
    r0s[tid] = tanhf(R0[tid]);
    __syncthreads();
    #pragma unroll
    for (int uu = 0; uu < 2; ++uu) {
        int u = tid + uu * 256;
        float acc = b_prep[u];
        for (int k = 0; k < 256; ++k)
            acc = fmaf(r0s[k], W_prep[(size_t)k * 512 + u], acc);
        ws[OFF_H0C + u] = acc;
    }
    for (int i = 0; i < 4; ++i) {
        float v = A0[i * 256 + tid];
        float mx = blk_reduce_max(v, red);
        float e = expf(v - mx);
        float s = blk_reduce_sum(e, red);
        ws[OFF_APREV + i * 256 + tid] = e / s;
    }
    float acc = 0.f;
    for (int m = 0; m < 128; ++m) {
        float t = m0[(size_t)tid * 128 + m];
        acc = fmaf(t, t, acc);
    }
    ws[OFF_MNORM + tid] = sqrtf(acc);
}

// Constant LSTM gate contributions: z0c (h0 + H0[0] rows of W_lstm[0] + b),
// z1c (H0[1] rows of W_lstm[1] + b)
__global__ __launch_bounds__(256) void k_const_b(
    const float* __restrict__ H0, const float* __restrict__ W_lstm,
    const float* __restrict__ b_lstm, float* __restrict__ ws)
{
    const int blk = blockIdx.x, tid = threadIdx.x;
    if (blk < 8) {
        int j = blk * 256 + tid;
        float acc = b_lstm[j];
        for (int u = 0; u < 512; ++u)
            acc = fmaf(ws[OFF_H0C + u], W_lstm[(size_t)(512 + u) * 2048 + j], acc);
        for (int u = 0; u < 512; ++u)
            acc = fmaf(H0[u], W_lstm[(size_t)(1024 + u) * 2048 + j], acc);
        ws[OFF_Z0C + j] = acc;
    } else {
        int j = (blk - 8) * 256 + tid;
        const float* W1 = W_lstm + (size_t)1536 * 2048;
        float acc = b_lstm[2048 + j];
        for (int u = 0; u < 512; ++u)
            acc = fmaf(H0[512 + u], W1[(size_t)(1024 + u) * 2048 + j], acc);
        ws[OFF_Z1C + j] = acc;
    }
}

// Copy X into XH[:, 0:512] (layer-1 GEMM input is [X | h1] contiguous)
__global__ void k_copyX(const float* __restrict__ X, float* __restrict__ xh)
{
    size_t idx = (size_t)blockIdx.x * blockDim.x + threadIdx.x;
    const size_t total = (size_t)Bn * 128;  // float4 count
    for (; idx < total; idx += (size_t)gridDim.x * blockDim.x) {
        size_t b = idx >> 7, q = idx & 127;
        reinterpret_cast<float4*>(xh)[b * 256 + q] =
            reinterpret_cast<const float4*>(X)[idx];
    }
}

// LSTM gate nonlinearity: z[B,2048] -> h[B] written at hout[b*ldh + u]
__global__ void k_gates(const float* __restrict__ z, const float* __restrict__ c0,
                        float* __restrict__ hout, int ldh, int doclip)
{
    size_t idx = (size_t)blockIdx.x * blockDim.x + threadIdx.x;
    const size_t total = (size_t)Bn * Un;
    for (; idx < total; idx += (size_t)gridDim.x * blockDim.x) {
        size_t b = idx >> 9, u = idx & 511;
        const float* zr = z + b * 2048;
        float ig = zr[u], fg = zr[512 + u], gg = zr[1024 + u], og = zr[1536 + u];
        float c = sigf(fg) * c0[u] + sigf(ig) * tanhf(gg);
        float h = sigf(og) * tanhf(c);
        if (doclip) h = fminf(fmaxf(h, -20.f), 20.f);
        hout[b * (size_t)ldh + u] = h;
    }
}

// Build combined head weight [512][1048] = [W_r | W_w], bias [1048]
__global__ void k_wrw(const float* __restrict__ W_r, const float* __restrict__ b_r,
                      const float* __restrict__ W_w, const float* __restrict__ b_w,
                      float* __restrict__ wrw, float* __restrict__ brw)
{
    size_t idx = (size_t)blockIdx.x * blockDim.x + threadIdx.x;
    const size_t total = (size_t)512 * 1048;
    for (; idx < total; idx += (size_t)gridDim.x * blockDim.x) {
        size_t u = idx / 1048, j = idx % 1048;
        wrw[idx] = (j < 268) ? W_r[u * 268 + j] : W_w[u * 780 + (j - 268)];
        if (idx < 1048) brw[idx] = (idx < 268) ? b_r[idx] : b_w[idx - 268];
    }
}

// m0 transpose [128][256] for the k @ m0^T GEMM
__global__ void k_m0T(const float* __restrict__ m0, float* __restrict__ m0t)
{
    int idx = blockIdx.x * blockDim.x + threadIdx.x;
    if (idx < 128 * 256) {
        int m = idx >> 8, n = idx & 255;
        m0t[idx] = m0[n * 128 + m];
    }
}

// Per-(b,head): k = tanh(hd[:128]) -> kbuf, knorm; for write heads also
// erase=sigmoid, add=tanh vectors.
__global__ __launch_bounds__(128) void k_kprep(
    const float* __restrict__ heads, float* __restrict__ kbuf,
    float* __restrict__ knorm, float* __restrict__ era, float* __restrict__ addv)
{
    __shared__ float red[128];
    const int b = blockIdx.x, i = blockIdx.y, tid = threadIdx.x;
    const int cb = (i < 2) ? i * 134 : 268 + (i - 2) * 390;
    const float* hd = heads + (size_t)b * 1048 + cb;
    float k = tanhf(hd[tid]);
    kbuf[((size_t)b * 4 + i) * 128 + tid] = k;
    float sq = blk_reduce_sum(k * k, red);
    if (tid == 0) knorm[b * 4 + i] = sqrtf(sq);
    if (i >= 2) {
        int ii = i - 2;
        era[((size_t)b * 2 + ii) * 128 + tid] = sigf(hd[134 + tid]);
        addv[((size_t)b * 2 + ii) * 128 + tid] = tanhf(hd[262 + tid]);
    }
}

// Addressing: cosine sim -> softmax -> interpolate -> circular conv -> sharpen
__global__ __launch_bounds__(256) void k_addr(
    const float* __restrict__ heads, const float* __restrict__ kmat,
    const float* __restrict__ knorm, const float* __restrict__ mnorm,
    const float* __restrict__ aprev, float* __restrict__ at)
{
    __shared__ float red[256];
    __shared__ float wgs[256];
    __shared__ float sc[6];
    const int b = blockIdx.x, i = blockIdx.y, tid = threadIdx.x;
    const int cb = (i < 2) ? i * 134 : 268 + (i - 2) * 390;
    const float* hd = heads + (size_t)b * 1048 + cb;
    if (tid == 0) {
        sc[0] = softplusf(hd[128]);                 // beta
        sc[1] = sigf(hd[129]);                      // g
        float v0 = hd[130], v1 = hd[131], v2 = hd[132];
        float mx = fmaxf(v0, fmaxf(v1, v2));
        float e0 = expf(v0 - mx), e1 = expf(v1 - mx), e2 = expf(v2 - mx);
        float ssum = e0 + e1 + e2;
        sc[2] = e0 / ssum; sc[3] = e1 / ssum; sc[4] = e2 / ssum;  // s
        sc[5] = softplusf(hd[133]);                 // gamma
    }
    __syncthreads();
    const float beta = sc[0], g = sc[1], s0 = sc[2], s1 = sc[3], s2 = sc[4],
                gamma = sc[5];
    float inner = kmat[((size_t)b * 4 + i) * 256 + tid];
    float kn = knorm[b * 4 + i];
    float K = inner / (kn * mnorm[tid] + 1e-8f);
    float x = beta * K;
    float mx = blk_reduce_max(x, red);
    float e = expf(x - mx);
    float se = blk_reduce_sum(e, red);
    float wc = e / se;
    float wg = g * wc + (1.f - g) * aprev[i * 256 + tid];
    wgs[tid] = wg;
    __syncthreads();
    // roll(+1)[n]=wg[n-1], roll(-1)[n]=wg[n+1]
    float wconv = s0 * wg + s1 * wgs[(tid + 255) & 255] + s2 * wgs[(tid + 1) & 255];
    float wsh = powf(wconv, gamma);
    float ssum = blk_reduce_sum(wsh, red);
    at[((size_t)i * Bn + b) * 256 + tid] = wsh / ssum;
}

// m_t = ((m0*(1-w0*e0)+w0*a0)*(1-w1*e1)+w1*a1), streamed float4
__global__ void k_mem(const float* __restrict__ m0, const float* __restrict__ at,
                      const float* __restrict__ era, const float* __restrict__ addv,
                      float* __restrict__ outm)
{
    const size_t total = (size_t)Bn * Nn * (Mn / 4);
    for (size_t idx = (size_t)blockIdx.x * blockDim.x + threadIdx.x;
         idx < total; idx += (size_t)gridDim.x * blockDim.x) {
        int mq = (int)(idx & 31);
        int n  = (int)((idx >> 5) & 255);
        int b  = (int)(idx >> 13);
        float4 t  = reinterpret_cast<const float4*>(m0)[n * 32 + mq];
        float w0 = at[((size_t)(2 * Bn) + b) * 256 + n];
        float w1 = at[((size_t)(3 * Bn) + b) * 256 + n];
        float4 e0 = reinterpret_cast<const float4*>(era)[((size_t)b * 2 + 0) * 32 + mq];
        float4 a0 = reinterpret_cast<const float4*>(addv)[((size_t)b * 2 + 0) * 32 + mq];
        float4 e1 = reinterpret_cast<const float4*>(era)[((size_t)b * 2 + 1) * 32 + mq];
        float4 a1 = reinterpret_cast<const float4*>(addv)[((size_t)b * 2 + 1) * 32 + mq];
#define UPD(c) { t.c = t.c * (1.f - w0 * e0.c) + w0 * a0.c; \
                 t.c = t.c * (1.f - w1 * e1.c) + w1 * a1.c; }
        UPD(x) UPD(y) UPD(z) UPD(w)
#undef UPD
        reinterpret_cast<float4*>(outm)[idx] = t;
    }
}

extern "C" void kernel_launch(void* const* d_in, const int* in_sizes, int n_in,
                              void* d_out, int out_size, void* d_ws, size_t ws_size,
                              hipStream_t stream)
{
    const float* X      = (const float*)d_in[0];
    const float* m0     = (const float*)d_in[1];
    const float* H0     = (const float*)d_in[2];
    const float* C0     = (const float*)d_in[3];
    const float* R0     = (const float*)d_in[4];
    const float* A0     = (const float*)d_in[5];
    const float* W_prep = (const float*)d_in[6];
    const float* b_prep = (const float*)d_in[7];
    const float* W_lstm = (const float*)d_in[8];
    const float* b_lstm = (const float*)d_in[9];
    const float* W_r    = (const float*)d_in[10];
    const float* b_r    = (const float*)d_in[11];
    const float* W_w    = (const float*)d_in[12];
    const float* b_w    = (const float*)d_in[13];
    const float* W_ou   = (const float*)d_in[14];
    const float* b_ou   = (const float*)d_in[15];
    float* ws  = (float*)d_ws;
    float* out = (float*)d_out;

    // Batch-invariant constants
    k_const_a<<<1, 256, 0, stream>>>(R0, W_prep, b_prep, A0, m0, ws);
    k_const_b<<<16, 256, 0, stream>>>(H0, W_lstm, b_lstm, ws);
    k_copyX<<<1024, 256, 0, stream>>>(X, ws + OFF_XH);

    // LSTM layer 0: z = X @ W0[0:512] + z0c ; gates -> h1 into XH[:,512:1024]
    gemm_f32<<<dim3(16, 16), 256, 0, stream>>>(
        X, 512, W_lstm, 2048, ws + OFF_Z0C, ws + OFF_ZBUF, 2048,
        Bn, 2048, 512, 0);
    k_gates<<<2048, 256, 0, stream>>>(ws + OFF_ZBUF, C0, ws + OFF_XH + 512, 1024, 0);

    // LSTM layer 1: z = [X|h1] @ W1[0:1024] + z1c ; gates+clip -> HR[:,0:512]
    gemm_f32<<<dim3(16, 16), 256, 0, stream>>>(
        ws + OFF_XH, 1024, W_lstm + (size_t)1536 * 2048, 2048, ws + OFF_Z1C,
        ws + OFF_ZBUF, 2048, Bn, 2048, 1024, 0);
    k_gates<<<2048, 256, 0, stream>>>(ws + OFF_ZBUF, C0 + 512, ws + OFF_HR, 768, 1);

    // Heads: [B,512] @ [512,1048] (+bias)
    k_wrw<<<2096, 256, 0, stream>>>(W_r, b_r, W_w, b_w, ws + OFF_WRW, ws + OFF_BRW);
    gemm_f32<<<dim3(16, 9), 256, 0, stream>>>(
        ws + OFF_HR, 768, ws + OFF_WRW, 1048, ws + OFF_BRW,
        ws + OFF_HEADS, 1048, Bn, 1048, 512, 0);

    // k vectors, norms, erase/add (kbuf aliases XH; free after layer-1 GEMM)
    k_kprep<<<dim3(Bn, 4), 128, 0, stream>>>(
        ws + OFF_HEADS, ws + OFF_XH, ws + OFF_KNORM, ws + OFF_ERA, ws + OFF_ADD);
    k_m0T<<<128, 256, 0, stream>>>(m0, ws + OFF_M0T);

    // inner[b,i,n] = k . m0[n]  : [8192,128] @ [128,256] (Kmat aliases ZBUF)
    gemm_f32<<<dim3(64, 2), 256, 0, stream>>>(
        ws + OFF_XH, 128, ws + OFF_M0T, 256, nullptr,
        ws + OFF_ZBUF, 256, Bn * 4, 256, 128, 0);

    // Addressing -> A_t[4][B][256]
    k_addr<<<dim3(Bn, 4), 256, 0, stream>>>(
        ws + OFF_HEADS, ws + OFF_ZBUF, ws + OFF_KNORM, ws + OFF_MNORM,
        ws + OFF_APREV, ws + OFF_AT);

    // Reads: R_t[i] = A_t[i] @ m0 -> HR[:, 512+i*128 : ...]
    gemm_f32<<<dim3(16, 1), 256, 0, stream>>>(
        ws + OFF_AT, 256, m0, 128, nullptr, ws + OFF_HR + 512, 768,
        Bn, 128, 256, 0);
    gemm_f32<<<dim3(16, 1), 256, 0, stream>>>(
        ws + OFF_AT + (size_t)Bn * 256, 256, m0, 128, nullptr,
        ws + OFF_HR + 640, 768, Bn, 128, 256, 0);

    // y = clip([h|R0|R1] @ W_ou + b_ou) -> d_out[0 : B*U]
    gemm_f32<<<dim3(16, 4), 256, 0, stream>>>(
        ws + OFF_HR, 768, W_ou, 512, b_ou, out, 512, Bn, 512, 768, 1);

    // m_t -> d_out[B*U : ]
    k_mem<<<2048, 256, 0, stream>>>(
        m0, ws + OFF_AT, ws + OFF_ERA, ws + OFF_ADD, out + (size_t)Bn * Un);
}

// Round 2
// 385.928 us; speedup vs baseline: 3.8158x; 3.8158x over previous
//
#include <hip/hip_runtime.h>
#include <math.h>

// Problem constants
static constexpr int Bn = 2048;   // batch
static constexpr int Nn = 256;    // memory locations
static constexpr int Mn = 128;    // memory width
static constexpr int Un = 512;    // units

// Workspace layout (float offsets)
static constexpr size_t OFF_H0C   = 0;       // 512
static constexpr size_t OFF_Z0C   = 512;     // 2048
static constexpr size_t OFF_Z1C   = 2560;    // 2048
static constexpr size_t OFF_MNORM = 4608;    // 256
static constexpr size_t OFF_APREV = 4864;    // 1024
static constexpr size_t OFF_BIASH = 5888;    // 1152
static constexpr size_t OFF_KNORM = 7040;    // 8192
static constexpr size_t OFF_Z     = 16384;    // f32 [2048][2048] z / kmat alias
static constexpr size_t OFF_KBUF  = 2113536;  // bf16 [8192][128] (upper half of Z)
static constexpr size_t OFF_HEADS = 4210688;  // f32 [2048][1048]
static constexpr size_t OFF_AT    = 6356992;  // f32 [4][2048][256]
static constexpr size_t OFF_ERA   = 8454144;  // f32 [2048][2][128]
static constexpr size_t OFF_ADD   = 8716288;  // f32 [2048][2][128]
static constexpr size_t OFF_XHB   = 8978432;  // bf16 [2048][1024] (atb alias later)
static constexpr size_t OFF_HB    = 10027008; // bf16 [2048][768]
static constexpr size_t OFF_W0T   = 10813440; // bf16 [2048][512]
static constexpr size_t OFF_W1T   = 11337728; // bf16 [2048][1024]
static constexpr size_t OFF_WRWT  = 12386304; // bf16 [1152][512]
static constexpr size_t OFF_WOUTT = 12681216; // bf16 [512][768]
static constexpr size_t OFF_M0B   = 12877824; // bf16 [256][128]
static constexpr size_t OFF_M0TB  = 12894208; // bf16 [128][256]

#define DEV __device__ __forceinline__

typedef __attribute__((ext_vector_type(8))) short bf16x8;
typedef __attribute__((ext_vector_type(4))) float f32x4;
typedef __attribute__((ext_vector_type(8))) unsigned short ushort8;
typedef __attribute__((ext_vector_type(4))) unsigned short ushort4v;

DEV float sigf(float x) { return 1.0f / (1.0f + expf(-x)); }
DEV float softplusf(float x) { return x > 20.0f ? x : log1pf(expf(x)); }
DEV unsigned short f2bf(float f) {   // RNE float->bf16
    unsigned u = __float_as_uint(f);
    u = (u + 0x7FFFu + ((u >> 16) & 1u)) >> 16;
    return (unsigned short)u;
}

DEV float blk_reduce_max(float v, float* red) {
    int tid = threadIdx.x;
    red[tid] = v; __syncthreads();
    for (int s = (int)blockDim.x >> 1; s > 0; s >>= 1) {
        if (tid < s) red[tid] = fmaxf(red[tid], red[tid + s]);
        __syncthreads();
    }
    float r = red[0]; __syncthreads();
    return r;
}
DEV float blk_reduce_sum(float v, float* red) {
    int tid = threadIdx.x;
    red[tid] = v; __syncthreads();
    for (int s = (int)blockDim.x >> 1; s > 0; s >>= 1) {
        if (tid < s) red[tid] += red[tid + s];
        __syncthreads();
    }
    float r = red[0]; __syncthreads();
    return r;
}

// ---------------------------------------------------------------------------
// bf16 MFMA GEMM: C[m,n] = sum_k A[m,k]*W[k,n]; A bf16 [M][lda],
// Wt bf16 [N][ldw] (W transposed). Tile 128x128, 4 waves, 16x16x32 MFMA.
// epi: 0=f32 out, 1=f32+clip, 2=bf16 out (Cb). M,K multiples of 128/32.
// ---------------------------------------------------------------------------
__global__ __launch_bounds__(256) void gemm_bf16(
    const unsigned short* __restrict__ A, int lda,
    const unsigned short* __restrict__ Wt, int ldw,
    const float* __restrict__ bias,
    float* __restrict__ C, unsigned short* __restrict__ Cb, int ldc,
    int Nr, int Kr, int epi)
{
    __shared__ __align__(16) unsigned short As[128 * 32];
    __shared__ __align__(16) unsigned short Ws[128 * 32];
    const int tid  = threadIdx.x;
    const int lane = tid & 63;
    const int wave = tid >> 6;
    const int wr = wave >> 1, wc = wave & 1;
    const int row0 = blockIdx.x * 128;
    const int col0 = blockIdx.y * 128;
    const int sr = tid >> 2;
    const int sk = (tid & 3) * 8;

    f32x4 acc[4][4];
    #pragma unroll
    for (int i = 0; i < 4; ++i)
        #pragma unroll
        for (int j = 0; j < 4; ++j) acc[i][j] = (f32x4){0.f, 0.f, 0.f, 0.f};

    const int frow = lane & 15;
    const int fk   = (lane >> 4) * 8;

    for (int k0 = 0; k0 < Kr; k0 += 32) {
        ushort8 a0 = *(const ushort8*)(A  + (size_t)(row0 + sr)      * lda + k0 + sk);
        ushort8 a1 = *(const ushort8*)(A  + (size_t)(row0 + sr + 64) * lda + k0 + sk);
        ushort8 w0 = *(const ushort8*)(Wt + (size_t)(col0 + sr)      * ldw + k0 + sk);
        ushort8 w1 = *(const ushort8*)(Wt + (size_t)(col0 + sr + 64) * ldw + k0 + sk);
        __syncthreads();
        *(ushort8*)&As[(sr)      * 32 + sk] = a0;
        *(ushort8*)&As[(sr + 64) * 32 + sk] = a1;
        *(ushort8*)&Ws[(sr)      * 32 + sk] = w0;
        *(ushort8*)&Ws[(sr + 64) * 32 + sk] = w1;
        __syncthreads();
        bf16x8 af[4], bfr[4];
        #pragma unroll
        for (int i = 0; i < 4; ++i)
            af[i] = *(const bf16x8*)&As[(wr * 64 + i * 16 + frow) * 32 + fk];
        #pragma unroll
        for (int j = 0; j < 4; ++j)
            bfr[j] = *(const bf16x8*)&Ws[(wc * 64 + j * 16 + frow) * 32 + fk];
        #pragma unroll
        for (int i = 0; i < 4; ++i)
            #pragma unroll
            for (int j = 0; j < 4; ++j)
                acc[i][j] = __builtin_amdgcn_mfma_f32_16x16x32_bf16(
                    af[i], bfr[j], acc[i][j], 0, 0, 0);
    }

    #pragma unroll
    for (int i = 0; i < 4; ++i) {
        int m0r = row0 + wr * 64 + i * 16 + (lane >> 4) * 4;
        #pragma unroll
        for (int j = 0; j < 4; ++j) {
            int n = col0 + wc * 64 + j * 16 + (lane & 15);
            if (n >= Nr) continue;
            float bv = bias ? bias[n] : 0.f;
            #pragma unroll
            for (int r = 0; r < 4; ++r) {
                float v = acc[i][j][r] + bv;
                if (epi == 1) v = fminf(fmaxf(v, -20.f), 20.f);
                if (epi == 2) Cb[(size_t)(m0r + r) * ldc + n] = f2bf(v);
                else          C [(size_t)(m0r + r) * ldc + n] = v;
            }
        }
    }
}

// f32 -> bf16 copy (8-wide), src [R][lds] -> dst [R][ldd]
__global__ void k_cvt8(const float* __restrict__ src, int lds,
                       unsigned short* __restrict__ dst, int ldd,
                       int c8, size_t total)
{
    for (size_t idx = (size_t)blockIdx.x * blockDim.x + threadIdx.x;
         idx < total; idx += (size_t)gridDim.x * blockDim.x) {
        size_t r = idx / c8, c = (idx % c8) * 8;
        const float* s = src + r * lds + c;
        float4 v0 = *(const float4*)s;
        float4 v1 = *(const float4*)(s + 4);
        ushort8 o;
        o[0] = f2bf(v0.x); o[1] = f2bf(v0.y); o[2] = f2bf(v0.z); o[3] = f2bf(v0.w);
        o[4] = f2bf(v1.x); o[5] = f2bf(v1.y); o[6] = f2bf(v1.z); o[7] = f2bf(v1.w);
        *(ushort8*)(dst + r * ldd + c) = o;
    }
}

// f32 -> bf16 transpose: src f32 [R][lds] -> dst bf16 [C][ldd]
__global__ void k_cvtT(const float* __restrict__ src, int R, int C, int lds,
                       unsigned short* __restrict__ dst, int ldd)
{
    __shared__ float t[32][33];
    const int bx = blockIdx.x * 32;   // over C
    const int by = blockIdx.y * 32;   // over R
    const int x = threadIdx.x;
    for (int y = threadIdx.y; y < 32; y += 8) {
        int r = by + y, c = bx + x;
        t[y][x] = (r < R && c < C) ? src[(size_t)r * lds + c] : 0.f;
    }
    __syncthreads();
    for (int y = threadIdx.y; y < 32; y += 8) {
        int c = bx + y, r = by + x;
        if (c < C && r < R) dst[(size_t)c * ldd + r] = f2bf(t[x][y]);
    }
}

// Batch-invariant constants
__global__ __launch_bounds__(256) void k_const_a(
    const float* __restrict__ R0, const float* __restrict__ W_prep,
    const float* __restrict__ b_prep, const float* __restrict__ A0,
    const float* __restrict__ m0, const float* __restrict__ b_r,
    const float* __restrict__ b_w, float* __restrict__ ws)
{
    __shared__ float r0s[256];
    __shared__ float red[256];
    const int tid = threadIdx.x;
    r0s[tid] = tanhf(R0[tid]);
    __syncthreads();
    #pragma unroll
    for (int uu = 0; uu < 2; ++uu) {
        int u = tid + uu * 256;
        float acc = b_prep[u];
        for (int k = 0; k < 256; ++k)
            acc = fmaf(r0s[k], W_prep[(size_t)k * 512 + u], acc);
        ws[OFF_H0C + u] = acc;
    }
    for (int i = 0; i < 4; ++i) {
        float v = A0[i * 256 + tid];
        float mx = blk_reduce_max(v, red);
        float e = expf(v - mx);
        float s = blk_reduce_sum(e, red);
        ws[OFF_APREV + i * 256 + tid] = e / s;
    }
    float acc = 0.f;
    for (int m = 0; m < 128; ++m) {
        float t = m0[(size_t)tid * 128 + m];
        acc = fmaf(t, t, acc);
    }
    ws[OFF_MNORM + tid] = sqrtf(acc);
    for (int j = tid; j < 1152; j += 256)
        ws[OFF_BIASH + j] = (j < 268) ? b_r[j] : (j < 1048 ? b_w[j - 268] : 0.f);
}

__global__ __launch_bounds__(256) void k_const_b(
    const float* __restrict__ H0, const float* __restrict__ W_lstm,
    const float* __restrict__ b_lstm, float* __restrict__ ws)
{
    const int blk = blockIdx.x, tid = threadIdx.x;
    if (blk < 8) {
        int j = blk * 256 + tid;
        float acc = b_lstm[j];
        for (int u = 0; u < 512; ++u)
            acc = fmaf(ws[OFF_H0C + u], W_lstm[(size_t)(512 + u) * 2048 + j], acc);
        for (int u = 0; u < 512; ++u)
            acc = fmaf(H0[u], W_lstm[(size_t)(1024 + u) * 2048 + j], acc);
        ws[OFF_Z0C + j] = acc;
    } else {
        int j = (blk - 8) * 256 + tid;
        const float* W1 = W_lstm + (size_t)1536 * 2048;
        float acc = b_lstm[2048 + j];
        for (int u = 0; u < 512; ++u)
            acc = fmaf(H0[512 + u], W1[(size_t)(1024 + u) * 2048 + j], acc);
        ws[OFF_Z1C + j] = acc;
    }
}

// LSTM gate nonlinearity: z[B,2048] -> h (bf16) at hout[b*ldh + u]
__global__ void k_gates(const float* __restrict__ z, const float* __restrict__ c0,
                        unsigned short* __restrict__ hout, int ldh, int doclip)
{
    const size_t total = (size_t)Bn * 128;
    for (size_t idx = (size_t)blockIdx.x * blockDim.x + threadIdx.x;
         idx < total; idx += (size_t)gridDim.x * blockDim.x) {
        size_t b = idx >> 7;
        int q = (int)(idx & 127) * 4;
        const float* zr = z + b * 2048;
        float4 ig = *(const float4*)(zr + q);
        float4 fg = *(const float4*)(zr + 512 + q);
        float4 gg = *(const float4*)(zr + 1024 + q);
        float4 og = *(const float4*)(zr + 1536 + q);
        float4 cc = *(const float4*)(c0 + q);
        ushort4v o;
        float c, h;
        c = sigf(fg.x) * cc.x + sigf(ig.x) * tanhf(gg.x);
        h = sigf(og.x) * tanhf(c); if (doclip) h = fminf(fmaxf(h, -20.f), 20.f);
        o[0] = f2bf(h);
        c = sigf(fg.y) * cc.y + sigf(ig.y) * tanhf(gg.y);
        h = sigf(og.y) * tanhf(c); if (doclip) h = fminf(fmaxf(h, -20.f), 20.f);
        o[1] = f2bf(h);
        c = sigf(fg.z) * cc.z + sigf(ig.z) * tanhf(gg.z);
        h = sigf(og.z) * tanhf(c); if (doclip) h = fminf(fmaxf(h, -20.f), 20.f);
        o[2] = f2bf(h);
        c = sigf(fg.w) * cc.w + sigf(ig.w) * tanhf(gg.w);
        h = sigf(og.w) * tanhf(c); if (doclip) h = fminf(fmaxf(h, -20.f), 20.f);
        o[3] = f2bf(h);
        *(ushort4v*)(hout + b * (size_t)ldh + q) = o;
    }
}

// Per-(b,head): k = tanh(hd[:128]) -> kbuf bf16, knorm; write heads: erase/add
__global__ __launch_bounds__(128) void k_kprep(
    const float* __restrict__ heads, unsigned short* __restrict__ kbuf,
    float* __restrict__ knorm, float* __restrict__ era, float* __restrict__ addv)
{
    __shared__ float red[128];
    const int b = blockIdx.x, i = blockIdx.y, tid = threadIdx.x;
    const int cb = (i < 2) ? i * 134 : 268 + (i - 2) * 390;
    const float* hd = heads + (size_t)b * 1048 + cb;
    float k = tanhf(hd[tid]);
    kbuf[((size_t)b * 4 + i) * 128 + tid] = f2bf(k);
    float sq = blk_reduce_sum(k * k, red);
    if (tid == 0) knorm[b * 4 + i] = sqrtf(sq);
    if (i >= 2) {
        int ii = i - 2;
        era [((size_t)b * 2 + ii) * 128 + tid] = sigf(hd[134 + tid]);
        addv[((size_t)b * 2 + ii) * 128 + tid] = tanhf(hd[262 + tid]);
    }
}

// Addressing
__global__ __launch_bounds__(256) void k_addr(
    const float* __restrict__ heads, const float* __restrict__ kmat,
    const float* __restrict__ knorm, const float* __restrict__ mnorm,
    const float* __restrict__ aprev, float* __restrict__ at,
    unsigned short* __restrict__ atb)
{
    __shared__ float red[256];
    __shared__ float wgs[256];
    __shared__ float sc[6];
    const int b = blockIdx.x, i = blockIdx.y, tid = threadIdx.x;
    const int cb = (i < 2) ? i * 134 : 268 + (i - 2) * 390;
    const float* hd = heads + (size_t)b * 1048 + cb;
    if (tid == 0) {
        sc[0] = softplusf(hd[128]);
        sc[1] = sigf(hd[129]);
        float v0 = hd[130], v1 = hd[131], v2 = hd[132];
        float mx = fmaxf(v0, fmaxf(v1, v2));
        float e0 = expf(v0 - mx), e1 = expf(v1 - mx), e2 = expf(v2 - mx);
        float ssum = e0 + e1 + e2;
        sc[2] = e0 / ssum; sc[3] = e1 / ssum; sc[4] = e2 / ssum;
        sc[5] = softplusf(hd[133]);
    }
    __syncthreads();
    const float beta = sc[0], g = sc[1], s0 = sc[2], s1 = sc[3], s2 = sc[4],
                gamma = sc[5];
    float inner = kmat[((size_t)b * 4 + i) * 256 + tid];
    float kn = knorm[b * 4 + i];
    float K = inner / (kn * mnorm[tid] + 1e-8f);
    float x = beta * K;
    float mx = blk_reduce_max(x, red);
    float e = expf(x - mx);
    float se = blk_reduce_sum(e, red);
    float wc = e / se;
    float wg = g * wc + (1.f - g) * aprev[i * 256 + tid];
    wgs[tid] = wg;
    __syncthreads();
    float wconv = s0 * wg + s1 * wgs[(tid + 255) & 255] + s2 * wgs[(tid + 1) & 255];
    float wsh = powf(wconv, gamma);
    float ssum = blk_reduce_sum(wsh, red);
    float w = wsh / ssum;
    at [((size_t)i * Bn + b) * 256 + tid] = w;
    atb[((size_t)i * Bn + b) * 256 + tid] = f2bf(w);
}

// m_t
__global__ void k_mem(const float* __restrict__ m0, const float* __restrict__ at,
                      const float* __restrict__ era, const float* __restrict__ addv,
                      float* __restrict__ outm)
{
    const size_t total = (size_t)Bn * Nn * (Mn / 4);
    for (size_t idx = (size_t)blockIdx.x * blockDim.x + threadIdx.x;
         idx < total; idx += (size_t)gridDim.x * blockDim.x) {
        int mq = (int)(idx & 31);
        int n  = (int)((idx >> 5) & 255);
        int b  = (int)(idx >> 13);
        float4 t  = reinterpret_cast<const float4*>(m0)[n * 32 + mq];
        float w0 = at[((size_t)(2 * Bn) + b) * 256 + n];
        float w1 = at[((size_t)(3 * Bn) + b) * 256 + n];
        float4 e0 = reinterpret_cast<const float4*>(era) [((size_t)b * 2 + 0) * 32 + mq];
        float4 a0 = reinterpret_cast<const float4*>(addv)[((size_t)b * 2 + 0) * 32 + mq];
        float4 e1 = reinterpret_cast<const float4*>(era) [((size_t)b * 2 + 1) * 32 + mq];
        float4 a1 = reinterpret_cast<const float4*>(addv)[((size_t)b * 2 + 1) * 32 + mq];
#define UPD(c) { t.c = t.c * (1.f - w0 * e0.c) + w0 * a0.c; \
                 t.c = t.c * (1.f - w1 * e1.c) + w1 * a1.c; }
        UPD(x) UPD(y) UPD(z) UPD(w)
#undef UPD
        reinterpret_cast<float4*>(outm)[idx] = t;
    }
}

extern "C" void kernel_launch(void* const* d_in, const int* in_sizes, int n_in,
                              void* d_out, int out_size, void* d_ws, size_t ws_size,
                              hipStream_t stream)
{
    const float* X      = (const float*)d_in[0];
    const float* m0     = (const float*)d_in[1];
    const float* H0     = (const float*)d_in[2];
    const float* C0     = (const float*)d_in[3];
    const float* R0     = (const float*)d_in[4];
    const float* A0     = (const float*)d_in[5];
    const float* W_prep = (const float*)d_in[6];
    const float* b_prep = (const float*)d_in[7];
    const float* W_lstm = (const float*)d_in[8];
    const float* b_lstm = (const float*)d_in[9];
    const float* W_r    = (const float*)d_in[10];
    const float* b_r    = (const float*)d_in[11];
    const float* W_w    = (const float*)d_in[12];
    const float* b_w    = (const float*)d_in[13];
    const float* W_ou   = (const float*)d_in[14];
    const float* b_ou   = (const float*)d_in[15];
    float* ws  = (float*)d_ws;
    float* out = (float*)d_out;

    unsigned short* XHb   = (unsigned short*)(ws + OFF_XHB);
    unsigned short* ATB   = (unsigned short*)(ws + OFF_XHB);   // alias, XHb dead by then
    unsigned short* HB    = (unsigned short*)(ws + OFF_HB);
    unsigned short* W0T   = (unsigned short*)(ws + OFF_W0T);
    unsigned short* W1T   = (unsigned short*)(ws + OFF_W1T);
    unsigned short* WRWT  = (unsigned short*)(ws + OFF_WRWT);
    unsigned short* WOUTT = (unsigned short*)(ws + OFF_WOUTT);
    unsigned short* M0B   = (unsigned short*)(ws + OFF_M0B);
    unsigned short* M0TB  = (unsigned short*)(ws + OFF_M0TB);
    unsigned short* KBUF  = (unsigned short*)(ws + OFF_KBUF);

    k_const_a<<<1, 256, 0, stream>>>(R0, W_prep, b_prep, A0, m0, b_r, b_w, ws);
    k_const_b<<<16, 256, 0, stream>>>(H0, W_lstm, b_lstm, ws);
    k_cvt8<<<1024, 256, 0, stream>>>(X, 512, XHb, 1024, 64, (size_t)Bn * 64);
    k_cvt8<<<32, 256, 0, stream>>>(m0, 128, M0B, 128, 16, (size_t)256 * 16);
    dim3 tb(32, 8);
    k_cvtT<<<dim3(64, 16), tb, 0, stream>>>(W_lstm, 512, 2048, 2048, W0T, 512);
    k_cvtT<<<dim3(64, 32), tb, 0, stream>>>(W_lstm + (size_t)1536 * 2048, 1024, 2048, 2048, W1T, 1024);
    k_cvtT<<<dim3(9, 16),  tb, 0, stream>>>(W_r, 512, 268, 268, WRWT, 512);
    k_cvtT<<<dim3(25, 16), tb, 0, stream>>>(W_w, 512, 780, 780, WRWT + (size_t)268 * 512, 512);
    k_cvtT<<<dim3(16, 24), tb, 0, stream>>>(W_ou, 768, 512, 512, WOUTT, 768);
    k_cvtT<<<dim3(4, 8),   tb, 0, stream>>>(m0, 256, 128, 128, M0TB, 256);

    // LSTM layer 0
    gemm_bf16<<<dim3(16, 16), 256, 0, stream>>>(
        XHb, 1024, W0T, 512, ws + OFF_Z0C, ws + OFF_Z, nullptr, 2048, 2048, 512, 0);
    k_gates<<<1024, 256, 0, stream>>>(ws + OFF_Z, C0, XHb + 512, 1024, 0);

    // LSTM layer 1
    gemm_bf16<<<dim3(16, 16), 256, 0, stream>>>(
        XHb, 1024, W1T, 1024, ws + OFF_Z1C, ws + OFF_Z, nullptr, 2048, 2048, 1024, 0);
    k_gates<<<1024, 256, 0, stream>>>(ws + OFF_Z, C0 + 512, HB, 768, 1);

    // Heads
    gemm_bf16<<<dim3(16, 9), 256, 0, stream>>>(
        HB, 768, WRWT, 512, ws + OFF_BIASH, ws + OFF_HEADS, nullptr, 1048, 1048, 512, 0);

    k_kprep<<<dim3(Bn, 4), 128, 0, stream>>>(
        ws + OFF_HEADS, KBUF, ws + OFF_KNORM, ws + OFF_ERA, ws + OFF_ADD);

    // inner = k . m0[n]
    gemm_bf16<<<dim3(64, 2), 256, 0, stream>>>(
        KBUF, 128, M0B, 128, nullptr, ws + OFF_Z, nullptr, 256, 256, 128, 0);

    k_addr<<<dim3(Bn, 4), 256, 0, stream>>>(
        ws + OFF_HEADS, ws + OFF_Z, ws + OFF_KNORM, ws + OFF_MNORM,
        ws + OFF_APREV, ws + OFF_AT, ATB);

    // Reads
    gemm_bf16<<<dim3(16, 1), 256, 0, stream>>>(
        ATB, 256, M0TB, 256, nullptr, nullptr, HB + 512, 768, 128, 256, 2);
    gemm_bf16<<<dim3(16, 1), 256, 0, stream>>>(
        ATB + (size_t)Bn * 256, 256, M0TB, 256, nullptr, nullptr, HB + 640, 768, 128, 256, 2);

    // Output y
    gemm_bf16<<<dim3(16, 4), 256, 0, stream>>>(
        HB, 768, WOUTT, 768, b_ou, out, nullptr, 512, 512, 768, 1);

    // m_t
    k_mem<<<2048, 256, 0, stream>>>(
        m0, ws + OFF_AT, ws + OFF_ERA, ws + OFF_ADD, out + (size_t)Bn * Un);
}